// Round 1
// baseline (700.786 us; speedup 1.0000x reference)
//
#include <hip/hip_runtime.h>

#define NN 2048
#define KK 20
#define BB 16
#define T0F 1.8f      // candidate prefilter threshold (fallback-safe)
#define CAP 128       // candidate capacity per wave
#define CSLOT 64      // incoming-list capacity per column (Poisson(20): P(>64)~6e-14)

typedef __attribute__((ext_vector_type(4))) float f32x4;

// ---------------------------------------------------------------------------
// Kernel 1: per-row exact top-K selection.
// v2: all 16 float4 loads issued up-front (max MLP), no key[32]/val[32]
// register arrays (the cold fallback re-reads global instead) -> no spill.
// Fast path: compact candidates (key >= T0F) to LDS, bisect over <=128 values.
// Fallback (statistically ~never, but exact): full bisection + tie handling,
// recomputing keys from global (row is L2-hot) each bisect step.
// Emits (idx,val) per row, column sums, and per-column incoming lists.
// ---------------------------------------------------------------------------
__global__ __launch_bounds__(256, 4) void topk_kernel(
    const float* __restrict__ A, const float* __restrict__ noise,
    int* __restrict__ sel_idx, float* __restrict__ sel_val,
    float* __restrict__ colsum, int* __restrict__ col_cnt,
    unsigned short* __restrict__ col_src)
{
    __shared__ float cand_key[4][CAP];
    __shared__ float cand_val[4][CAP];
    __shared__ int   cand_idx[4][CAP];
    __shared__ int   tie_idx[4][64];
    __shared__ int   tie_cnt[4];

    const int lane = threadIdx.x & 63;
    const int wv   = threadIdx.x >> 6;
    const int row  = blockIdx.x * 4 + wv;          // 0 .. 32767
    const float* Ar = A     + (size_t)row * NN;
    const float* Nr = noise + (size_t)row * NN;
    const int colbase = row & ~(NN - 1);           // b * N
    const unsigned long long ltm = (1ull << lane) - 1ull;

    int*   si = sel_idx + (size_t)row * KK;
    float* sv = sel_val + (size_t)row * KK;

#define EMIT(POS, IDX, V)                                                      \
    do {                                                                       \
        int _p = (POS); int _i = (IDX); float _v = (V);                        \
        si[_p] = _i; sv[_p] = _v;                                              \
        atomicAdd(&colsum[colbase + _i], _v);                                  \
        int _s = atomicAdd(&col_cnt[colbase + _i], 1);                         \
        if (_s < CSLOT)                                                        \
            col_src[(size_t)(colbase + _i) * CSLOT + _s] =                     \
                (unsigned short)(((row & (NN - 1)) << 5) | _p);                \
    } while (0)

    // ---- Load burst: 16 independent dwordx4 loads, all in flight ----------
    float4 a[8], z[8];
#pragma unroll
    for (int c = 0; c < 8; ++c) a[c] = *(const float4*)(Ar + c * 256 + lane * 4);
#pragma unroll
    for (int c = 0; c < 8; ++c) z[c] = *(const float4*)(Nr + c * 256 + lane * 4);

    // ---- Phase 1: compact candidates (key >= T0F) into LDS ----------------
    // a[c]/z[c] are consumed exactly once here; no persistent key/val arrays.
    int cnt = 0;
#pragma unroll
    for (int c = 0; c < 8; ++c) {
        float av[4] = {a[c].x, a[c].y, a[c].z, a[c].w};
        float nv[4] = {z[c].x, z[c].y, z[c].z, z[c].w};
#pragma unroll
        for (int q = 0; q < 4; ++q) {
            float v = fmaxf(av[q], 0.f);
            float k = v + nv[q] * 1e-4f;
            bool p = k >= T0F;
            unsigned long long m = __ballot(p);
            if (p) {
                int pos = cnt + __popcll(m & ltm);
                if (pos < CAP) {
                    cand_key[wv][pos] = k;
                    cand_val[wv][pos] = v;
                    cand_idx[wv][pos] = c * 256 + lane * 4 + q;
                }
            }
            cnt += __popcll(m);
        }
    }

    bool done = false;
    if (cnt == KK) {
        // Candidates ARE the top-K.
        if (lane < KK)
            EMIT(lane, cand_idx[wv][lane], cand_val[wv][lane]);
        done = true;
    } else if (cnt > KK && cnt <= CAP) {
        // ---- Phase 2: bisect threshold over <=128 candidates --------------
        float c0 = (lane      < cnt) ? cand_key[wv][lane]      : -1.f;
        float c1 = (lane + 64 < cnt) ? cand_key[wv][lane + 64] : -1.f;

        float mx = fmaxf(c0, c1);
#pragma unroll
        for (int s = 32; s; s >>= 1) mx = fmaxf(mx, __shfl_xor(mx, s));

        unsigned lo = __float_as_uint(T0F);       // count(>=T0F)=cnt > K
        unsigned hi = __float_as_uint(mx) + 1u;   // count(>=f(hi)) = 0 < K
        bool exact = false; unsigned tb = 0;
        while (hi - lo > 1u) {
            unsigned mid = (lo + hi) >> 1;
            float tm = __uint_as_float(mid);
            int c = __popcll(__ballot(c0 >= tm)) + __popcll(__ballot(c1 >= tm));
            if (c == KK) { tb = mid; exact = true; break; }
            if (c > KK) lo = mid; else hi = mid;
        }
        if (exact) {
            float t = __uint_as_float(tb);
            bool p = c0 >= t;
            unsigned long long m = __ballot(p);
            if (p) EMIT(__popcll(m & ltm), cand_idx[wv][lane], cand_val[wv][lane]);
            int run = __popcll(m);
            p = c1 >= t;
            m = __ballot(p);
            if (p) EMIT(run + __popcll(m & ltm), cand_idx[wv][lane + 64],
                        cand_val[wv][lane + 64]);
            done = true;
        }
    }

    if (!done) {
        // ---- Fallback (cold, register-light): exact full-array bisection --
        // Re-reads the row from global (L2-hot) instead of holding 64 regs.
        unsigned lo = 0u, hi = 0x7F800000u;
        unsigned tb = 0u;
        bool exact = false;
        while (hi - lo > 1u) {
            unsigned mid = (lo + hi) >> 1;
            float tm = __uint_as_float(mid);
            int c = 0;
            for (int j = 0; j < 32; ++j) {
                float av = Ar[j * 64 + lane];
                float nv = Nr[j * 64 + lane];
                float k = fmaxf(av, 0.f) + nv * 1e-4f;
                c += __popcll(__ballot(k >= tm));
            }
            if (c == KK) { tb = mid; exact = true; break; }
            if (c > KK) lo = mid; else hi = mid;
        }
        if (exact) {
            float t = __uint_as_float(tb);
            int run = 0;
            for (int j = 0; j < 32; ++j) {
                float av = Ar[j * 64 + lane];
                float nv = Nr[j * 64 + lane];
                float v = fmaxf(av, 0.f);
                float k = v + nv * 1e-4f;
                bool p = k >= t;
                unsigned long long m = __ballot(p);
                if (p) EMIT(run + __popcll(m & ltm), j * 64 + lane, v);
                run += __popcll(m);
            }
        } else {
            // Exact tie at the K/K+1 boundary: strictly-greater first, then
            // fill ascending-index among ties (lax.top_k semantics).
            float t1 = __uint_as_float(lo);
            int run = 0;
            for (int j = 0; j < 32; ++j) {
                float av = Ar[j * 64 + lane];
                float nv = Nr[j * 64 + lane];
                float v = fmaxf(av, 0.f);
                float k = v + nv * 1e-4f;
                bool p = k > t1;
                unsigned long long m = __ballot(p);
                if (p) EMIT(run + __popcll(m & ltm), j * 64 + lane, v);
                run += __popcll(m);
            }
            if (lane == 0) tie_cnt[wv] = 0;
            for (int j = 0; j < 32; ++j) {
                float av = Ar[j * 64 + lane];
                float nv = Nr[j * 64 + lane];
                float k = fmaxf(av, 0.f) + nv * 1e-4f;
                if (k == t1) {
                    int p = atomicAdd(&tie_cnt[wv], 1);
                    if (p < 64) tie_idx[wv][p] = j * 64 + lane;
                }
            }
            if (lane == 0) {
                int n = tie_cnt[wv]; if (n > 64) n = 64;
                int need = KK - run;
                for (int s = 0; s < need; ++s) {
                    int bq = 0, bidx = 0x7fffffff;
                    for (int q = 0; q < n; ++q) {
                        int v = tie_idx[wv][q];
                        if (v < bidx) { bidx = v; bq = q; }
                    }
                    tie_idx[wv][bq] = 0x7fffffff;
                    float v = fmaxf(Ar[bidx], 0.f);
                    EMIT(run + s, bidx, v);
                }
            }
        }
    }
#undef EMIT
}

// ---------------------------------------------------------------------------
// Kernel 2: dinv = (1 + 0.5*(rowsum + colsum))^-1/2.
// ---------------------------------------------------------------------------
__global__ __launch_bounds__(256) void dinv_kernel(
    const float* __restrict__ sel_val, const float* __restrict__ colsum,
    float* __restrict__ dinv)
{
    int r = blockIdx.x * 256 + threadIdx.x;        // 0 .. 32767
    const float* svp = sel_val + (size_t)r * KK;
    float rs = 0.f;
#pragma unroll
    for (int k = 0; k < KK; ++k) rs += svp[k];
    float d = 1.0f + 0.5f * (rs + colsum[r]);
    dinv[r] = 1.0f / sqrtf(d);                     // d >= 1 always
}

// ---------------------------------------------------------------------------
// Kernel 3: one block per output row. Zero 8KB LDS row, add diagonal +
// outgoing + incoming contributions via LDS atomics, stream row out densely.
// v2: nontemporal row stores — the 256 MB output is write-once, never
// re-read; keep it out of L2 so sel_val/dinv/col_src reads stay cached.
// ---------------------------------------------------------------------------
__global__ __launch_bounds__(256) void dense_row_kernel(
    const int* __restrict__ sel_idx, const float* __restrict__ sel_val,
    const int* __restrict__ col_cnt, const unsigned short* __restrict__ col_src,
    const float* __restrict__ dinv, float* __restrict__ out)
{
    __shared__ float rowbuf[NN];
    const int r = blockIdx.x;                      // 0 .. 32767
    const int i = r & (NN - 1);
    const int t = threadIdx.x;
    const int colbase = r & ~(NN - 1);

    float4 zz = {0.f, 0.f, 0.f, 0.f};
#pragma unroll
    for (int c = 0; c < 2; ++c)
        *(float4*)(rowbuf + c * 1024 + t * 4) = zz;
    __syncthreads();

    float di = dinv[r];
    if (t == 0) atomicAdd(&rowbuf[i], di * di);    // (A+I) diagonal term
    if (t < KK) {
        int j  = sel_idx[(size_t)r * KK + t];
        float v = sel_val[(size_t)r * KK + t];
        atomicAdd(&rowbuf[j], 0.5f * v * di * dinv[colbase + j]);
    }
    int cnt = col_cnt[r]; if (cnt > CSLOT) cnt = CSLOT;
    if (t < cnt) {
        unsigned short pk = col_src[(size_t)r * CSLOT + t];
        int srow = pk >> 5, k = pk & 31;
        float v = sel_val[(size_t)(colbase + srow) * KK + k];
        atomicAdd(&rowbuf[srow], 0.5f * v * di * dinv[colbase + srow]);
    }
    __syncthreads();

    size_t base = (size_t)r * NN;
#pragma unroll
    for (int c = 0; c < 2; ++c) {
        int col = c * 1024 + t * 4;
        f32x4 v = *(const f32x4*)(rowbuf + col);
        __builtin_nontemporal_store(v, (f32x4*)(out + base + col));
    }
}

// ---------------------------------------------------------------------------
extern "C" void kernel_launch(void* const* d_in, const int* in_sizes, int n_in,
                              void* d_out, int out_size, void* d_ws, size_t ws_size,
                              hipStream_t stream)
{
    const float* A     = (const float*)d_in[0];
    const float* noise = (const float*)d_in[1];
    float* out = (float*)d_out;
    char*  ws  = (char*)d_ws;

    const int rows = BB * NN;                      // 32768
    // workspace layout (~9.4 MB total)
    size_t off = 0;
    int*   sel_idx = (int*)(ws + off);            off += (size_t)rows * KK * 4;   // 2.62 MB
    float* sel_val = (float*)(ws + off);          off += (size_t)rows * KK * 4;   // 2.62 MB
    float* colsum  = (float*)(ws + off);          off += (size_t)rows * 4;        // 128 KB
    float* dinv    = (float*)(ws + off);          off += (size_t)rows * 4;        // 128 KB
    int*   col_cnt = (int*)(ws + off);            off += (size_t)rows * 4;        // 128 KB
    unsigned short* col_src = (unsigned short*)(ws + off);                        // 4 MB

    hipMemsetAsync(colsum, 0, rows * sizeof(float), stream);
    hipMemsetAsync(col_cnt, 0, rows * sizeof(int), stream);

    topk_kernel<<<rows / 4, 256, 0, stream>>>(A, noise, sel_idx, sel_val,
                                              colsum, col_cnt, col_src);
    dinv_kernel<<<rows / 256, 256, 0, stream>>>(sel_val, colsum, dinv);
    dense_row_kernel<<<rows, 256, 0, stream>>>(sel_idx, sel_val, col_cnt,
                                               col_src, dinv, out);
}

// Round 2
// 662.251 us; speedup vs baseline: 1.0582x; 1.0582x over previous
//
#include <hip/hip_runtime.h>

#define NN 2048
#define KK 20
#define BB 16
#define T0F 1.8f              // key-space threshold (fallback-safe)
#define TPRE (T0F - 1.1e-4f)  // v-space prefilter: key>=T0F => v >= T0F-1e-4 (noise<1)
#define CAP 128               // candidate capacity per wave
#define CSLOT 64              // incoming-list capacity per column
#define RPW 4                 // rows per wave (topk)
#define DRROWS 8              // rows per block (dense_row)

typedef __attribute__((ext_vector_type(4))) float f32x4;

// ---------------------------------------------------------------------------
// Kernel 1: per-row exact top-K selection.
// v3: (a) prefilter on relu(A) alone -> noise is GATHERED at ~74 candidate
// positions instead of streamed (input bytes 16KB -> ~11.6KB per row);
// (b) 4 rows per wave with next-row A prefetch overlapping bisect/emit;
// (c) unordered LDS-atomic compaction (emission order is irrelevant: the
// reference scatters a 0/1 mask) replaces the serial 32-ballot prefix chain.
// Fallback (statistically ~never, exact): full-row re-read bisection + ties.
// ---------------------------------------------------------------------------
__global__ __launch_bounds__(256) void topk_kernel(
    const float* __restrict__ A, const float* __restrict__ noise,
    int* __restrict__ sel_idx, float* __restrict__ sel_val,
    float* __restrict__ colsum, int* __restrict__ col_cnt,
    unsigned short* __restrict__ col_src)
{
    __shared__ int   cand_idx[4][CAP];
    __shared__ float cand_val[4][CAP];
    __shared__ int   cand_cnt[4];
    __shared__ int   tie_idx[4][64];
    __shared__ int   tie_cnt[4];

    const int lane = threadIdx.x & 63;
    const int wv   = threadIdx.x >> 6;
    const unsigned long long ltm = (1ull << lane) - 1ull;

    if (lane == 0) cand_cnt[wv] = 0;   // same-wave DS ops are in-order

    int base = 0;                      // running LDS-counter base for this wave

    // Prologue: issue row rr=0 A-loads.
    {
        const float* Ar0 = A + (size_t)(blockIdx.x * (4 * RPW) + wv) * NN;
        // loaded below via the same a[] path
    }
    float4 a[8];
    {
        const float* Ar0 = A + (size_t)(blockIdx.x * (4 * RPW) + wv) * NN;
#pragma unroll
        for (int c = 0; c < 8; ++c)
            a[c] = *(const float4*)(Ar0 + c * 256 + lane * 4);
    }

#define EMIT(POS, IDX, V)                                                      \
    do {                                                                       \
        int _p = (POS); int _i = (IDX); float _v = (V);                        \
        si[_p] = _i; sv[_p] = _v;                                              \
        atomicAdd(&colsum[colbase + _i], _v);                                  \
        int _s = atomicAdd(&col_cnt[colbase + _i], 1);                         \
        if (_s < CSLOT)                                                        \
            col_src[(size_t)(colbase + _i) * CSLOT + _s] =                     \
                (unsigned short)(((row & (NN - 1)) << 5) | _p);                \
    } while (0)

#pragma unroll
    for (int rr = 0; rr < RPW; ++rr) {
        const int row = blockIdx.x * (4 * RPW) + rr * 4 + wv;
        const float* Ar = A     + (size_t)row * NN;
        const float* Nr = noise + (size_t)row * NN;
        const int colbase = row & ~(NN - 1);
        int*   si = sel_idx + (size_t)row * KK;
        float* sv = sel_val + (size_t)row * KK;

        // ---- Phase 1: compact v-candidates into LDS (unordered) -----------
        int mycnt = 0;
#pragma unroll
        for (int c = 0; c < 8; ++c) {
            float av[4] = {a[c].x, a[c].y, a[c].z, a[c].w};
#pragma unroll
            for (int q = 0; q < 4; ++q) {
                float v = fmaxf(av[q], 0.f);
                if (v >= TPRE) {
                    int p = atomicAdd(&cand_cnt[wv], 1) - base;
                    if (p < CAP) {
                        cand_idx[wv][p] = c * 256 + lane * 4 + q;
                        cand_val[wv][p] = v;
                    }
                    ++mycnt;
                }
            }
        }

        // ---- Prefetch next row's A (a[] is dead now) ----------------------
        if (rr + 1 < RPW) {
            const float* An = A + (size_t)(row + 4) * NN;
#pragma unroll
            for (int c = 0; c < 8; ++c)
                a[c] = *(const float4*)(An + c * 256 + lane * 4);
        }

        // wave-total candidate count (uniform)
        int cnt = mycnt;
#pragma unroll
        for (int s = 32; s; s >>= 1) cnt += __shfl_xor(cnt, s);
        base += cnt;

        bool done = false;
        if (cnt <= CAP) {
            // ---- Gather noise at candidate positions, form exact keys -----
            int   i0 = (lane      < cnt) ? cand_idx[wv][lane]      : -1;
            int   i1 = (lane + 64 < cnt) ? cand_idx[wv][lane + 64] : -1;
            float v0 = (i0 >= 0) ? cand_val[wv][lane]      : 0.f;
            float v1 = (i1 >= 0) ? cand_val[wv][lane + 64] : 0.f;
            float k0 = -1.f, k1 = -1.f;
            if (i0 >= 0) k0 = v0 + Nr[i0] * 1e-4f;
            if (i1 >= 0) k1 = v1 + Nr[i1] * 1e-4f;

            int cntK = __popcll(__ballot(k0 >= T0F)) +
                       __popcll(__ballot(k1 >= T0F));

            if (cntK == KK) {
                // keys >= T0F are exactly the top-K
                bool p = k0 >= T0F;
                unsigned long long m = __ballot(p);
                if (p) EMIT(__popcll(m & ltm), i0, v0);
                int run = __popcll(m);
                p = k1 >= T0F; m = __ballot(p);
                if (p) EMIT(run + __popcll(m & ltm), i1, v1);
                done = true;
            } else if (cntK > KK) {
                // ---- Phase 2: bisect threshold over candidate keys --------
                float mx = fmaxf(k0, k1);
#pragma unroll
                for (int s = 32; s; s >>= 1) mx = fmaxf(mx, __shfl_xor(mx, s));

                unsigned lo = __float_as_uint(T0F);     // count(>=T0F)=cntK > K
                unsigned hi = __float_as_uint(mx) + 1u; // count = 0 < K
                bool exact = false; unsigned tb = 0;
                while (hi - lo > 1u) {
                    unsigned mid = (lo + hi) >> 1;
                    float tm = __uint_as_float(mid);
                    int c = __popcll(__ballot(k0 >= tm)) +
                            __popcll(__ballot(k1 >= tm));
                    if (c == KK) { tb = mid; exact = true; break; }
                    if (c > KK) lo = mid; else hi = mid;
                }
                if (exact) {
                    float t = __uint_as_float(tb);
                    bool p = k0 >= t;
                    unsigned long long m = __ballot(p);
                    if (p) EMIT(__popcll(m & ltm), i0, v0);
                    int run = __popcll(m);
                    p = k1 >= t; m = __ballot(p);
                    if (p) EMIT(run + __popcll(m & ltm), i1, v1);
                    done = true;
                }
            }
        }

        if (!done) {
            // ---- Fallback (cold, exact): full-row re-read bisection -------
            unsigned lo = 0u, hi = 0x7F800000u;
            unsigned tb = 0u;
            bool exact = false;
            while (hi - lo > 1u) {
                unsigned mid = (lo + hi) >> 1;
                float tm = __uint_as_float(mid);
                int c = 0;
                for (int j = 0; j < 32; ++j) {
                    float av = Ar[j * 64 + lane];
                    float nv = Nr[j * 64 + lane];
                    float k = fmaxf(av, 0.f) + nv * 1e-4f;
                    c += __popcll(__ballot(k >= tm));
                }
                if (c == KK) { tb = mid; exact = true; break; }
                if (c > KK) lo = mid; else hi = mid;
            }
            if (exact) {
                float t = __uint_as_float(tb);
                int run = 0;
                for (int j = 0; j < 32; ++j) {
                    float av = Ar[j * 64 + lane];
                    float nv = Nr[j * 64 + lane];
                    float v = fmaxf(av, 0.f);
                    float k = v + nv * 1e-4f;
                    bool p = k >= t;
                    unsigned long long m = __ballot(p);
                    if (p) EMIT(run + __popcll(m & ltm), j * 64 + lane, v);
                    run += __popcll(m);
                }
            } else {
                // Exact tie at the K/K+1 boundary: strictly-greater first,
                // then ascending-index among ties (lax.top_k semantics).
                float t1 = __uint_as_float(lo);
                int run = 0;
                for (int j = 0; j < 32; ++j) {
                    float av = Ar[j * 64 + lane];
                    float nv = Nr[j * 64 + lane];
                    float v = fmaxf(av, 0.f);
                    float k = v + nv * 1e-4f;
                    bool p = k > t1;
                    unsigned long long m = __ballot(p);
                    if (p) EMIT(run + __popcll(m & ltm), j * 64 + lane, v);
                    run += __popcll(m);
                }
                if (lane == 0) tie_cnt[wv] = 0;
                for (int j = 0; j < 32; ++j) {
                    float av = Ar[j * 64 + lane];
                    float nv = Nr[j * 64 + lane];
                    float k = fmaxf(av, 0.f) + nv * 1e-4f;
                    if (k == t1) {
                        int p = atomicAdd(&tie_cnt[wv], 1);
                        if (p < 64) tie_idx[wv][p] = j * 64 + lane;
                    }
                }
                if (lane == 0) {
                    int n = tie_cnt[wv]; if (n > 64) n = 64;
                    int need = KK - run;
                    for (int s = 0; s < need; ++s) {
                        int bq = 0, bidx = 0x7fffffff;
                        for (int q = 0; q < n; ++q) {
                            int v = tie_idx[wv][q];
                            if (v < bidx) { bidx = v; bq = q; }
                        }
                        tie_idx[wv][bq] = 0x7fffffff;
                        float v = fmaxf(Ar[bidx], 0.f);
                        EMIT(run + s, bidx, v);
                    }
                }
            }
        }
    }
#undef EMIT
}

// ---------------------------------------------------------------------------
// Kernel 2: dinv = (1 + 0.5*(rowsum + colsum))^-1/2.
// ---------------------------------------------------------------------------
__global__ __launch_bounds__(256) void dinv_kernel(
    const float* __restrict__ sel_val, const float* __restrict__ colsum,
    float* __restrict__ dinv)
{
    int r = blockIdx.x * 256 + threadIdx.x;        // 0 .. 32767
    const float* svp = sel_val + (size_t)r * KK;
    float rs = 0.f;
#pragma unroll
    for (int k = 0; k < KK; ++k) rs += svp[k];
    float d = 1.0f + 0.5f * (rs + colsum[r]);
    dinv[r] = 1.0f / sqrtf(d);                     // d >= 1 always
}

// ---------------------------------------------------------------------------
// Kernel 3: v3 — each block builds DRROWS consecutive rows sequentially
// (grid 32768 -> 4096): keeps NT-store streams resident per CU instead of
// one-shot 8KB blocks. Zero LDS row, add diagonal + outgoing + incoming via
// LDS atomics, stream out with nontemporal float4 stores.
// Hazard note: between rows, each thread zeroes only the rowbuf words it
// itself just streamed out (same-thread ordering), and all scattered atomics
// sit between the two __syncthreads.
// ---------------------------------------------------------------------------
__global__ __launch_bounds__(256) void dense_row_kernel(
    const int* __restrict__ sel_idx, const float* __restrict__ sel_val,
    const int* __restrict__ col_cnt, const unsigned short* __restrict__ col_src,
    const float* __restrict__ dinv, float* __restrict__ out)
{
    __shared__ float rowbuf[NN];
    const int t = threadIdx.x;

#pragma unroll 1
    for (int it = 0; it < DRROWS; ++it) {
        const int r = blockIdx.x * DRROWS + it;    // 0 .. 32767
        const int i = r & (NN - 1);
        const int colbase = r & ~(NN - 1);

        f32x4 zz = {0.f, 0.f, 0.f, 0.f};
        *(f32x4*)(rowbuf + t * 4) = zz;
        *(f32x4*)(rowbuf + 1024 + t * 4) = zz;
        __syncthreads();

        float di = dinv[r];
        if (t == 0) atomicAdd(&rowbuf[i], di * di);        // (A+I) diagonal
        if (t < KK) {
            int j  = sel_idx[(size_t)r * KK + t];
            float v = sel_val[(size_t)r * KK + t];
            atomicAdd(&rowbuf[j], 0.5f * v * di * dinv[colbase + j]);
        }
        int cnt = col_cnt[r]; if (cnt > CSLOT) cnt = CSLOT;
        if (t < cnt) {
            unsigned short pk = col_src[(size_t)r * CSLOT + t];
            int srow = pk >> 5, k = pk & 31;
            float v = sel_val[(size_t)(colbase + srow) * KK + k];
            atomicAdd(&rowbuf[srow], 0.5f * v * di * dinv[colbase + srow]);
        }
        __syncthreads();

        size_t bb = (size_t)r * NN;
        f32x4 lo = *(const f32x4*)(rowbuf + t * 4);
        f32x4 hi = *(const f32x4*)(rowbuf + 1024 + t * 4);
        __builtin_nontemporal_store(lo, (f32x4*)(out + bb + t * 4));
        __builtin_nontemporal_store(hi, (f32x4*)(out + bb + 1024 + t * 4));
    }
}

// ---------------------------------------------------------------------------
extern "C" void kernel_launch(void* const* d_in, const int* in_sizes, int n_in,
                              void* d_out, int out_size, void* d_ws, size_t ws_size,
                              hipStream_t stream)
{
    const float* A     = (const float*)d_in[0];
    const float* noise = (const float*)d_in[1];
    float* out = (float*)d_out;
    char*  ws  = (char*)d_ws;

    const int rows = BB * NN;                      // 32768
    // workspace layout (~9.4 MB total)
    size_t off = 0;
    int*   sel_idx = (int*)(ws + off);            off += (size_t)rows * KK * 4;   // 2.62 MB
    float* sel_val = (float*)(ws + off);          off += (size_t)rows * KK * 4;   // 2.62 MB
    float* colsum  = (float*)(ws + off);          off += (size_t)rows * 4;        // 128 KB
    float* dinv    = (float*)(ws + off);          off += (size_t)rows * 4;        // 128 KB
    int*   col_cnt = (int*)(ws + off);            off += (size_t)rows * 4;        // 128 KB
    unsigned short* col_src = (unsigned short*)(ws + off);                        // 4 MB

    hipMemsetAsync(colsum, 0, rows * sizeof(float), stream);
    hipMemsetAsync(col_cnt, 0, rows * sizeof(int), stream);

    topk_kernel<<<rows / (4 * RPW), 256, 0, stream>>>(A, noise, sel_idx, sel_val,
                                                      colsum, col_cnt, col_src);
    dinv_kernel<<<rows / 256, 256, 0, stream>>>(sel_val, colsum, dinv);
    dense_row_kernel<<<rows / DRROWS, 256, 0, stream>>>(sel_idx, sel_val, col_cnt,
                                                        col_src, dinv, out);
}

// Round 3
// 641.748 us; speedup vs baseline: 1.0920x; 1.0319x over previous
//
#include <hip/hip_runtime.h>

#define NN 2048
#define KK 20
#define BB 16
#define TPRE 1.79989f   // relu(A) prefilter; key>=1.8 => v>=1.8-1e-4 (noise<1)
#define CAP 128         // candidate capacity per wave (mean ~74, 6.4 sigma)
#define CSLOT 64        // incoming-list capacity per column

typedef __attribute__((ext_vector_type(4))) float f32x4;

// ---------------------------------------------------------------------------
// Kernel 1: per-row exact top-K selection. One wave per row.
// v4: ballot-prefix compaction (conflict-free, scalar-only serial part) +
// noise gathered at the ~74 candidate positions + RANK-BASED selection:
//   rank(x) = #{y : key_y > key_x or (key_y==key_x and idx_y < idx_x)}
//   selected iff rank < K; emit slot = rank.
// One pipelined pass over <=CAP broadcast LDS reads replaces the ~20-step
// serial bisection, and is exact under ties (lax.top_k low-index preference;
// the reference only consumes the index SET). Fallback only for cnt<K or
// cnt>CAP (P ~ 1e-10/row): full-row bisection + tie handling, re-reading
// global (row is L2/L3-hot).
// ---------------------------------------------------------------------------
__global__ __launch_bounds__(256) void topk_kernel(
    const float* __restrict__ A, const float* __restrict__ noise,
    int* __restrict__ sel_idx, float* __restrict__ sel_val,
    float* __restrict__ colsum, int* __restrict__ col_cnt,
    unsigned short* __restrict__ col_src)
{
    __shared__ float cand_key[4][CAP];
    __shared__ float cand_val[4][CAP];
    __shared__ int   cand_idx[4][CAP];
    __shared__ int   tie_idx[4][64];
    __shared__ int   tie_cnt[4];

    const int lane = threadIdx.x & 63;
    const int wv   = threadIdx.x >> 6;
    const int row  = blockIdx.x * 4 + wv;          // 0 .. 32767
    const float* Ar = A     + (size_t)row * NN;
    const float* Nr = noise + (size_t)row * NN;
    const int colbase = row & ~(NN - 1);           // b * N
    const unsigned long long ltm = (1ull << lane) - 1ull;

    int*   si = sel_idx + (size_t)row * KK;
    float* sv = sel_val + (size_t)row * KK;

#define EMIT(POS, IDX, V)                                                      \
    do {                                                                       \
        int _p = (POS); int _i = (IDX); float _v = (V);                        \
        si[_p] = _i; sv[_p] = _v;                                              \
        atomicAdd(&colsum[colbase + _i], _v);                                  \
        int _s = atomicAdd(&col_cnt[colbase + _i], 1);                         \
        if (_s < CSLOT)                                                        \
            col_src[(size_t)(colbase + _i) * CSLOT + _s] =                     \
                (unsigned short)(((row & (NN - 1)) << 5) | _p);                \
    } while (0)

    // ---- Load burst: 8 independent dwordx4 loads --------------------------
    float4 a[8];
#pragma unroll
    for (int c = 0; c < 8; ++c)
        a[c] = *(const float4*)(Ar + c * 256 + lane * 4);

    // ---- Phase 1: ballot-prefix compaction of v-candidates into LDS -------
    int cnt = 0;
#pragma unroll
    for (int c = 0; c < 8; ++c) {
        float av[4] = {a[c].x, a[c].y, a[c].z, a[c].w};
#pragma unroll
        for (int q = 0; q < 4; ++q) {
            float v = fmaxf(av[q], 0.f);
            bool p = v >= TPRE;
            unsigned long long m = __ballot(p);
            if (p) {
                int pos = cnt + __popcll(m & ltm);
                if (pos < CAP) {
                    cand_val[wv][pos] = v;
                    cand_idx[wv][pos] = c * 256 + lane * 4 + q;
                }
            }
            cnt += __popcll(m);
        }
    }

    bool done = false;
    if (cnt >= KK && cnt <= CAP) {
        // ---- Gather noise at candidate positions, form exact keys ---------
        int   i0 = (lane      < cnt) ? cand_idx[wv][lane]      : -1;
        int   i1 = (lane + 64 < cnt) ? cand_idx[wv][lane + 64] : -1;
        float v0 = (i0 >= 0) ? cand_val[wv][lane]      : 0.f;
        float v1 = (i1 >= 0) ? cand_val[wv][lane + 64] : 0.f;
        float k0 = -1.f, k1 = -1.f;
        if (i0 >= 0) k0 = fmaf(Nr[i0], 1e-4f, v0);
        if (i1 >= 0) k1 = fmaf(Nr[i1], 1e-4f, v1);
        cand_key[wv][lane]      = k0;   // wave-synchronous LDS: no barrier
        cand_key[wv][lane + 64] = k1;

        // ---- Rank pass: one pipelined scan, no serial cross-lane chain ----
        int r0 = 0, r1 = 0;
        for (int j = 0; j < cnt; ++j) {
            float kj = cand_key[wv][j];   // broadcast (conflict-free)
            int   ij = cand_idx[wv][j];
            r0 += (kj > k0) || (kj == k0 && ij < i0);
            r1 += (kj > k1) || (kj == k1 && ij < i1);
        }
        if (i0 >= 0 && r0 < KK) EMIT(r0, i0, v0);
        if (i1 >= 0 && r1 < KK) EMIT(r1, i1, v1);
        done = true;
    }

    if (!done) {
        // ---- Fallback (cold, exact): full-row re-read bisection -----------
        unsigned lo = 0u, hi = 0x7F800000u;
        unsigned tb = 0u;
        bool exact = false;
        while (hi - lo > 1u) {
            unsigned mid = (lo + hi) >> 1;
            float tm = __uint_as_float(mid);
            int c = 0;
            for (int j = 0; j < 32; ++j) {
                float av = Ar[j * 64 + lane];
                float nv = Nr[j * 64 + lane];
                float k = fmaf(nv, 1e-4f, fmaxf(av, 0.f));
                c += __popcll(__ballot(k >= tm));
            }
            if (c == KK) { tb = mid; exact = true; break; }
            if (c > KK) lo = mid; else hi = mid;
        }
        if (exact) {
            float t = __uint_as_float(tb);
            int run = 0;
            for (int j = 0; j < 32; ++j) {
                float av = Ar[j * 64 + lane];
                float nv = Nr[j * 64 + lane];
                float v = fmaxf(av, 0.f);
                float k = fmaf(nv, 1e-4f, v);
                bool p = k >= t;
                unsigned long long m = __ballot(p);
                if (p) EMIT(run + __popcll(m & ltm), j * 64 + lane, v);
                run += __popcll(m);
            }
        } else {
            // Exact tie at the K/K+1 boundary: strictly-greater first, then
            // ascending-index among ties (lax.top_k semantics).
            float t1 = __uint_as_float(lo);
            int run = 0;
            for (int j = 0; j < 32; ++j) {
                float av = Ar[j * 64 + lane];
                float nv = Nr[j * 64 + lane];
                float v = fmaxf(av, 0.f);
                float k = fmaf(nv, 1e-4f, v);
                bool p = k > t1;
                unsigned long long m = __ballot(p);
                if (p) EMIT(run + __popcll(m & ltm), j * 64 + lane, v);
                run += __popcll(m);
            }
            if (lane == 0) tie_cnt[wv] = 0;
            for (int j = 0; j < 32; ++j) {
                float av = Ar[j * 64 + lane];
                float nv = Nr[j * 64 + lane];
                float k = fmaf(nv, 1e-4f, fmaxf(av, 0.f));
                if (k == t1) {
                    int p = atomicAdd(&tie_cnt[wv], 1);
                    if (p < 64) tie_idx[wv][p] = j * 64 + lane;
                }
            }
            if (lane == 0) {
                int n = tie_cnt[wv]; if (n > 64) n = 64;
                int need = KK - run;
                for (int s = 0; s < need; ++s) {
                    int bq = 0, bidx = 0x7fffffff;
                    for (int q = 0; q < n; ++q) {
                        int v = tie_idx[wv][q];
                        if (v < bidx) { bidx = v; bq = q; }
                    }
                    tie_idx[wv][bq] = 0x7fffffff;
                    float v = fmaxf(Ar[bidx], 0.f);
                    EMIT(run + s, bidx, v);
                }
            }
        }
    }
#undef EMIT
}

// ---------------------------------------------------------------------------
// Kernel 2: dinv = (1 + 0.5*(rowsum + colsum))^-1/2.
// ---------------------------------------------------------------------------
__global__ __launch_bounds__(256) void dinv_kernel(
    const float* __restrict__ sel_val, const float* __restrict__ colsum,
    float* __restrict__ dinv)
{
    int r = blockIdx.x * 256 + threadIdx.x;        // 0 .. 32767
    const float* svp = sel_val + (size_t)r * KK;
    float rs = 0.f;
#pragma unroll
    for (int k = 0; k < KK; ++k) rs += svp[k];
    float d = 1.0f + 0.5f * (rs + colsum[r]);
    dinv[r] = 1.0f / sqrtf(d);                     // d >= 1 always
}

// ---------------------------------------------------------------------------
// Kernel 3: one block per output row (round-0 structure — best measured;
// NT stores and row-batching both regressed ~25us, reverted). v4 change:
// issue ALL scattered reads before the LDS zeroing so their latency hides
// under the zero + barrier instead of serializing after it.
// ---------------------------------------------------------------------------
__global__ __launch_bounds__(256) void dense_row_kernel(
    const int* __restrict__ sel_idx, const float* __restrict__ sel_val,
    const int* __restrict__ col_cnt, const unsigned short* __restrict__ col_src,
    const float* __restrict__ dinv, float* __restrict__ out)
{
    __shared__ float rowbuf[NN];
    const int r = blockIdx.x;                      // 0 .. 32767
    const int i = r & (NN - 1);
    const int t = threadIdx.x;
    const int colbase = r & ~(NN - 1);

    // ---- Early-issue scattered reads (latency hides under zero+barrier) ---
    float di = dinv[r];
    int jo = 0; float vo = 0.f, djo = 0.f;
    if (t < KK) {
        jo  = sel_idx[(size_t)r * KK + t];
        vo  = sel_val[(size_t)r * KK + t];
        djo = dinv[colbase + jo];
    }
    int cnt = col_cnt[r]; if (cnt > CSLOT) cnt = CSLOT;
    int srow = 0; float vi = 0.f, dji = 0.f;
    if (t < cnt) {
        unsigned short pk = col_src[(size_t)r * CSLOT + t];
        srow = pk >> 5;
        int k = pk & 31;
        vi  = sel_val[(size_t)(colbase + srow) * KK + k];
        dji = dinv[colbase + srow];
    }

    float4 zz = {0.f, 0.f, 0.f, 0.f};
#pragma unroll
    for (int c = 0; c < 2; ++c)
        *(float4*)(rowbuf + c * 1024 + t * 4) = zz;
    __syncthreads();

    if (t == 0) atomicAdd(&rowbuf[i], di * di);    // (A+I) diagonal term
    if (t < KK)  atomicAdd(&rowbuf[jo],   0.5f * vo * di * djo);
    if (t < cnt) atomicAdd(&rowbuf[srow], 0.5f * vi * di * dji);
    __syncthreads();

    size_t base = (size_t)r * NN;
#pragma unroll
    for (int c = 0; c < 2; ++c) {
        int col = c * 1024 + t * 4;
        *(float4*)(out + base + col) = *(const float4*)(rowbuf + col);
    }
}

// ---------------------------------------------------------------------------
extern "C" void kernel_launch(void* const* d_in, const int* in_sizes, int n_in,
                              void* d_out, int out_size, void* d_ws, size_t ws_size,
                              hipStream_t stream)
{
    const float* A     = (const float*)d_in[0];
    const float* noise = (const float*)d_in[1];
    float* out = (float*)d_out;
    char*  ws  = (char*)d_ws;

    const int rows = BB * NN;                      // 32768
    // workspace layout (~9.4 MB total)
    size_t off = 0;
    int*   sel_idx = (int*)(ws + off);            off += (size_t)rows * KK * 4;   // 2.62 MB
    float* sel_val = (float*)(ws + off);          off += (size_t)rows * KK * 4;   // 2.62 MB
    float* colsum  = (float*)(ws + off);          off += (size_t)rows * 4;        // 128 KB
    float* dinv    = (float*)(ws + off);          off += (size_t)rows * 4;        // 128 KB
    int*   col_cnt = (int*)(ws + off);            off += (size_t)rows * 4;        // 128 KB
    unsigned short* col_src = (unsigned short*)(ws + off);                        // 4 MB

    hipMemsetAsync(colsum, 0, rows * sizeof(float), stream);
    hipMemsetAsync(col_cnt, 0, rows * sizeof(int), stream);

    topk_kernel<<<rows / 4, 256, 0, stream>>>(A, noise, sel_idx, sel_val,
                                              colsum, col_cnt, col_src);
    dinv_kernel<<<rows / 256, 256, 0, stream>>>(sel_val, colsum, dinv);
    dense_row_kernel<<<rows, 256, 0, stream>>>(sel_idx, sel_val, col_cnt,
                                               col_src, dinv, out);
}

// Round 4
// 635.832 us; speedup vs baseline: 1.1022x; 1.0093x over previous
//
#include <hip/hip_runtime.h>

#define NN 2048
#define KK 20
#define BB 16
#define TPRE 1.79989f   // relu(A) prefilter; key>=1.8 => v>=1.8-1e-4 (noise<1)
#define CAP 128         // candidate capacity per wave (mean ~74, 6.4 sigma)
#define CSLOT 64        // incoming-list capacity per column

typedef __attribute__((ext_vector_type(4))) float f32x4;

// ---------------------------------------------------------------------------
// Kernel 1: per-row exact top-K selection. One wave per row.
// v5: rank-based selection on PACKED u64 keys.
//   packed = (float_bits(key) << 32) | (NN-1-idx)   (key>0 => bits monotonic)
//   rank(x) = #{y : packed_y > packed_x};  selected iff rank < K; slot = rank.
// The u64 low word implements lax.top_k's low-index tie preference exactly.
// Rank scan is unrolled x8 over broadcast ds_read_b64 (half the LDS ops of
// v4's key+idx reads, and loads pipeline instead of load->compare chains).
// Fallback only for cnt<K or cnt>CAP (P ~ 1e-10/row): full-row bisection +
// tie handling, re-reading global (row is L2/L3-hot).
// ---------------------------------------------------------------------------
__global__ __launch_bounds__(256) void topk_kernel(
    const float* __restrict__ A, const float* __restrict__ noise,
    int* __restrict__ sel_idx, float* __restrict__ sel_val,
    float* __restrict__ colsum, int* __restrict__ col_cnt,
    unsigned short* __restrict__ col_src)
{
    __shared__ unsigned long long cand_pk[4][CAP + 8];
    __shared__ float cand_val[4][CAP];
    __shared__ int   cand_idx[4][CAP];
    __shared__ int   tie_idx[4][64];
    __shared__ int   tie_cnt[4];

    const int lane = threadIdx.x & 63;
    const int wv   = threadIdx.x >> 6;
    const int row  = blockIdx.x * 4 + wv;          // 0 .. 32767
    const float* Ar = A     + (size_t)row * NN;
    const float* Nr = noise + (size_t)row * NN;
    const int colbase = row & ~(NN - 1);           // b * N
    const unsigned long long ltm = (1ull << lane) - 1ull;

    int*   si = sel_idx + (size_t)row * KK;
    float* sv = sel_val + (size_t)row * KK;

#define EMIT(POS, IDX, V)                                                      \
    do {                                                                       \
        int _p = (POS); int _i = (IDX); float _v = (V);                        \
        si[_p] = _i; sv[_p] = _v;                                              \
        atomicAdd(&colsum[colbase + _i], _v);                                  \
        int _s = atomicAdd(&col_cnt[colbase + _i], 1);                         \
        if (_s < CSLOT)                                                        \
            col_src[(size_t)(colbase + _i) * CSLOT + _s] =                     \
                (unsigned short)(((row & (NN - 1)) << 5) | _p);                \
    } while (0)

    // ---- Load burst: 8 independent dwordx4 loads --------------------------
    float4 a[8];
#pragma unroll
    for (int c = 0; c < 8; ++c)
        a[c] = *(const float4*)(Ar + c * 256 + lane * 4);

    // ---- Phase 1: ballot-prefix compaction of v-candidates into LDS -------
    int cnt = 0;
#pragma unroll
    for (int c = 0; c < 8; ++c) {
        float av[4] = {a[c].x, a[c].y, a[c].z, a[c].w};
#pragma unroll
        for (int q = 0; q < 4; ++q) {
            float v = fmaxf(av[q], 0.f);
            bool p = v >= TPRE;
            unsigned long long m = __ballot(p);
            if (p) {
                int pos = cnt + __popcll(m & ltm);
                if (pos < CAP) {
                    cand_val[wv][pos] = v;
                    cand_idx[wv][pos] = c * 256 + lane * 4 + q;
                }
            }
            cnt += __popcll(m);
        }
    }

    bool done = false;
    if (cnt >= KK && cnt <= CAP) {
        // ---- Gather noise at candidate positions, pack sortable u64 -------
        int   i0 = (lane      < cnt) ? cand_idx[wv][lane]      : -1;
        int   i1 = (lane + 64 < cnt) ? cand_idx[wv][lane + 64] : -1;
        float v0 = (i0 >= 0) ? cand_val[wv][lane]      : 0.f;
        float v1 = (i1 >= 0) ? cand_val[wv][lane + 64] : 0.f;
        unsigned long long pk0 = ~0ull, pk1 = ~0ull;
        if (i0 >= 0) {
            float k0 = fmaf(Nr[i0], 1e-4f, v0);
            pk0 = ((unsigned long long)__float_as_uint(k0) << 32)
                | (unsigned)(NN - 1 - i0);
            cand_pk[wv][lane] = pk0;
        }
        if (i1 >= 0) {
            float k1 = fmaf(Nr[i1], 1e-4f, v1);
            pk1 = ((unsigned long long)__float_as_uint(k1) << 32)
                | (unsigned)(NN - 1 - i1);
            cand_pk[wv][lane + 64] = pk1;
        }
        // sentinel pad to multiple of 8 (0 < any real packed key)
        int nIter = (cnt + 7) & ~7;
        if (lane < nIter - cnt) cand_pk[wv][cnt + lane] = 0ull;

        // ---- Rank scan: unrolled x8, broadcast b64 reads, pipelined -------
        int r0 = 0, r1 = 0;
        for (int j = 0; j < nIter; j += 8) {
            unsigned long long b[8];
#pragma unroll
            for (int u = 0; u < 8; ++u) b[u] = cand_pk[wv][j + u];
#pragma unroll
            for (int u = 0; u < 8; ++u) {
                r0 += (b[u] > pk0);
                r1 += (b[u] > pk1);
            }
        }
        if (i0 >= 0 && r0 < KK) EMIT(r0, i0, v0);
        if (i1 >= 0 && r1 < KK) EMIT(r1, i1, v1);
        done = true;
    }

    if (!done) {
        // ---- Fallback (cold, exact): full-row re-read bisection -----------
        unsigned lo = 0u, hi = 0x7F800000u;
        unsigned tb = 0u;
        bool exact = false;
        while (hi - lo > 1u) {
            unsigned mid = (lo + hi) >> 1;
            float tm = __uint_as_float(mid);
            int c = 0;
            for (int j = 0; j < 32; ++j) {
                float av = Ar[j * 64 + lane];
                float nv = Nr[j * 64 + lane];
                float k = fmaf(nv, 1e-4f, fmaxf(av, 0.f));
                c += __popcll(__ballot(k >= tm));
            }
            if (c == KK) { tb = mid; exact = true; break; }
            if (c > KK) lo = mid; else hi = mid;
        }
        if (exact) {
            float t = __uint_as_float(tb);
            int run = 0;
            for (int j = 0; j < 32; ++j) {
                float av = Ar[j * 64 + lane];
                float nv = Nr[j * 64 + lane];
                float v = fmaxf(av, 0.f);
                float k = fmaf(nv, 1e-4f, v);
                bool p = k >= t;
                unsigned long long m = __ballot(p);
                if (p) EMIT(run + __popcll(m & ltm), j * 64 + lane, v);
                run += __popcll(m);
            }
        } else {
            // Exact tie at the K/K+1 boundary: strictly-greater first, then
            // ascending-index among ties (lax.top_k semantics).
            float t1 = __uint_as_float(lo);
            int run = 0;
            for (int j = 0; j < 32; ++j) {
                float av = Ar[j * 64 + lane];
                float nv = Nr[j * 64 + lane];
                float v = fmaxf(av, 0.f);
                float k = fmaf(nv, 1e-4f, v);
                bool p = k > t1;
                unsigned long long m = __ballot(p);
                if (p) EMIT(run + __popcll(m & ltm), j * 64 + lane, v);
                run += __popcll(m);
            }
            if (lane == 0) tie_cnt[wv] = 0;
            for (int j = 0; j < 32; ++j) {
                float av = Ar[j * 64 + lane];
                float nv = Nr[j * 64 + lane];
                float k = fmaf(nv, 1e-4f, fmaxf(av, 0.f));
                if (k == t1) {
                    int p = atomicAdd(&tie_cnt[wv], 1);
                    if (p < 64) tie_idx[wv][p] = j * 64 + lane;
                }
            }
            if (lane == 0) {
                int n = tie_cnt[wv]; if (n > 64) n = 64;
                int need = KK - run;
                for (int s = 0; s < need; ++s) {
                    int bq = 0, bidx = 0x7fffffff;
                    for (int q = 0; q < n; ++q) {
                        int v = tie_idx[wv][q];
                        if (v < bidx) { bidx = v; bq = q; }
                    }
                    tie_idx[wv][bq] = 0x7fffffff;
                    float v = fmaxf(Ar[bidx], 0.f);
                    EMIT(run + s, bidx, v);
                }
            }
        }
    }
#undef EMIT
}

// ---------------------------------------------------------------------------
// Kernel 2: dinv = (1 + 0.5*(rowsum + colsum))^-1/2.
// ---------------------------------------------------------------------------
__global__ __launch_bounds__(256) void dinv_kernel(
    const float* __restrict__ sel_val, const float* __restrict__ colsum,
    float* __restrict__ dinv)
{
    int r = blockIdx.x * 256 + threadIdx.x;        // 0 .. 32767
    const float* svp = sel_val + (size_t)r * KK;
    float rs = 0.f;
#pragma unroll
    for (int k = 0; k < KK; ++k) rs += svp[k];
    float d = 1.0f + 0.5f * (rs + colsum[r]);
    dinv[r] = 1.0f / sqrtf(d);                     // d >= 1 always
}

// ---------------------------------------------------------------------------
// Kernel 3: one block per output row — EXACT round-0 structure (best
// measured; NT stores, row-batching, and early-issue reads each regressed
// 20-30us across rounds 1-3; do not touch).
// ---------------------------------------------------------------------------
__global__ __launch_bounds__(256) void dense_row_kernel(
    const int* __restrict__ sel_idx, const float* __restrict__ sel_val,
    const int* __restrict__ col_cnt, const unsigned short* __restrict__ col_src,
    const float* __restrict__ dinv, float* __restrict__ out)
{
    __shared__ float rowbuf[NN];
    const int r = blockIdx.x;                      // 0 .. 32767
    const int i = r & (NN - 1);
    const int t = threadIdx.x;
    const int colbase = r & ~(NN - 1);

    float4 z = {0.f, 0.f, 0.f, 0.f};
#pragma unroll
    for (int c = 0; c < 2; ++c)
        *(float4*)(rowbuf + c * 1024 + t * 4) = z;
    __syncthreads();

    float di = dinv[r];
    if (t == 0) atomicAdd(&rowbuf[i], di * di);    // (A+I) diagonal term
    if (t < KK) {
        int j  = sel_idx[(size_t)r * KK + t];
        float v = sel_val[(size_t)r * KK + t];
        atomicAdd(&rowbuf[j], 0.5f * v * di * dinv[colbase + j]);
    }
    int cnt = col_cnt[r]; if (cnt > CSLOT) cnt = CSLOT;
    if (t < cnt) {
        unsigned short pk = col_src[(size_t)r * CSLOT + t];
        int srow = pk >> 5, k = pk & 31;
        float v = sel_val[(size_t)(colbase + srow) * KK + k];
        atomicAdd(&rowbuf[srow], 0.5f * v * di * dinv[colbase + srow]);
    }
    __syncthreads();

    size_t base = (size_t)r * NN;
#pragma unroll
    for (int c = 0; c < 2; ++c) {
        int col = c * 1024 + t * 4;
        *(float4*)(out + base + col) = *(const float4*)(rowbuf + col);
    }
}

// ---------------------------------------------------------------------------
extern "C" void kernel_launch(void* const* d_in, const int* in_sizes, int n_in,
                              void* d_out, int out_size, void* d_ws, size_t ws_size,
                              hipStream_t stream)
{
    const float* A     = (const float*)d_in[0];
    const float* noise = (const float*)d_in[1];
    float* out = (float*)d_out;
    char*  ws  = (char*)d_ws;

    const int rows = BB * NN;                      // 32768
    // workspace layout (~9.4 MB total)
    size_t off = 0;
    int*   sel_idx = (int*)(ws + off);            off += (size_t)rows * KK * 4;   // 2.62 MB
    float* sel_val = (float*)(ws + off);          off += (size_t)rows * KK * 4;   // 2.62 MB
    float* colsum  = (float*)(ws + off);          off += (size_t)rows * 4;        // 128 KB
    float* dinv    = (float*)(ws + off);          off += (size_t)rows * 4;        // 128 KB
    int*   col_cnt = (int*)(ws + off);            off += (size_t)rows * 4;        // 128 KB
    unsigned short* col_src = (unsigned short*)(ws + off);                        // 4 MB

    hipMemsetAsync(colsum, 0, rows * sizeof(float), stream);
    hipMemsetAsync(col_cnt, 0, rows * sizeof(int), stream);

    topk_kernel<<<rows / 4, 256, 0, stream>>>(A, noise, sel_idx, sel_val,
                                              colsum, col_cnt, col_src);
    dinv_kernel<<<rows / 256, 256, 0, stream>>>(sel_val, colsum, dinv);
    dense_row_kernel<<<rows, 256, 0, stream>>>(sel_idx, sel_val, col_cnt,
                                               col_src, dinv, out);
}

// Round 5
// 619.496 us; speedup vs baseline: 1.1312x; 1.0264x over previous
//
#include <hip/hip_runtime.h>

#define NN 2048
#define KK 20
#define BB 16
#define TPRE 1.79989f   // relu(A) prefilter; key>=1.8 => v>=1.8-1e-4 (noise<1)
#define CAP 128         // candidate capacity per wave (mean ~74, 6.4 sigma)

typedef __attribute__((ext_vector_type(4))) float f32x4;

// ---------------------------------------------------------------------------
// Kernel 1: per-row exact top-K selection. One wave per row.
// v6 = v5 (rank-based selection on packed u64 keys, measured 169us) with the
// EMIT slimmed to 2 stores + 1 fire-and-forget colsum atomic: the
// incoming-list machinery (col_cnt atomic-with-return + col_src scatter
// writes, ~42MB of partial-line writebacks) is gone — the output is now
// built by a global scatter kernel instead of per-row gather.
//   packed = (float_bits(key) << 32) | (NN-1-idx)   (key>0 => bits monotonic)
//   rank(x) = #{y : packed_y > packed_x};  selected iff rank < K; slot = rank.
// Fallback only for cnt<K or cnt>CAP (P ~ 1e-10/row): full-row bisection +
// tie handling, re-reading global (row is L2/L3-hot).
// ---------------------------------------------------------------------------
__global__ __launch_bounds__(256) void topk_kernel(
    const float* __restrict__ A, const float* __restrict__ noise,
    int* __restrict__ sel_idx, float* __restrict__ sel_val,
    float* __restrict__ colsum)
{
    __shared__ unsigned long long cand_pk[4][CAP + 8];
    __shared__ float cand_val[4][CAP];
    __shared__ int   cand_idx[4][CAP];
    __shared__ int   tie_idx[4][64];
    __shared__ int   tie_cnt[4];

    const int lane = threadIdx.x & 63;
    const int wv   = threadIdx.x >> 6;
    const int row  = blockIdx.x * 4 + wv;          // 0 .. 32767
    const float* Ar = A     + (size_t)row * NN;
    const float* Nr = noise + (size_t)row * NN;
    const int colbase = row & ~(NN - 1);           // b * N
    const unsigned long long ltm = (1ull << lane) - 1ull;

    int*   si = sel_idx + (size_t)row * KK;
    float* sv = sel_val + (size_t)row * KK;

#define EMIT(POS, IDX, V)                                                      \
    do {                                                                       \
        int _p = (POS); int _i = (IDX); float _v = (V);                        \
        si[_p] = _i; sv[_p] = _v;                                              \
        atomicAdd(&colsum[colbase + _i], _v);                                  \
    } while (0)

    // ---- Load burst: 8 independent dwordx4 loads --------------------------
    float4 a[8];
#pragma unroll
    for (int c = 0; c < 8; ++c)
        a[c] = *(const float4*)(Ar + c * 256 + lane * 4);

    // ---- Phase 1: ballot-prefix compaction of v-candidates into LDS -------
    int cnt = 0;
#pragma unroll
    for (int c = 0; c < 8; ++c) {
        float av[4] = {a[c].x, a[c].y, a[c].z, a[c].w};
#pragma unroll
        for (int q = 0; q < 4; ++q) {
            float v = fmaxf(av[q], 0.f);
            bool p = v >= TPRE;
            unsigned long long m = __ballot(p);
            if (p) {
                int pos = cnt + __popcll(m & ltm);
                if (pos < CAP) {
                    cand_val[wv][pos] = v;
                    cand_idx[wv][pos] = c * 256 + lane * 4 + q;
                }
            }
            cnt += __popcll(m);
        }
    }

    bool done = false;
    if (cnt >= KK && cnt <= CAP) {
        // ---- Gather noise at candidate positions, pack sortable u64 -------
        int   i0 = (lane      < cnt) ? cand_idx[wv][lane]      : -1;
        int   i1 = (lane + 64 < cnt) ? cand_idx[wv][lane + 64] : -1;
        float v0 = (i0 >= 0) ? cand_val[wv][lane]      : 0.f;
        float v1 = (i1 >= 0) ? cand_val[wv][lane + 64] : 0.f;
        unsigned long long pk0 = ~0ull, pk1 = ~0ull;
        if (i0 >= 0) {
            float k0 = fmaf(Nr[i0], 1e-4f, v0);
            pk0 = ((unsigned long long)__float_as_uint(k0) << 32)
                | (unsigned)(NN - 1 - i0);
            cand_pk[wv][lane] = pk0;
        }
        if (i1 >= 0) {
            float k1 = fmaf(Nr[i1], 1e-4f, v1);
            pk1 = ((unsigned long long)__float_as_uint(k1) << 32)
                | (unsigned)(NN - 1 - i1);
            cand_pk[wv][lane + 64] = pk1;
        }
        // sentinel pad to multiple of 8 (0 < any real packed key)
        int nIter = (cnt + 7) & ~7;
        if (lane < nIter - cnt) cand_pk[wv][cnt + lane] = 0ull;

        // ---- Rank scan: unrolled x8, broadcast b64 reads, pipelined -------
        int r0 = 0, r1 = 0;
        for (int j = 0; j < nIter; j += 8) {
            unsigned long long b[8];
#pragma unroll
            for (int u = 0; u < 8; ++u) b[u] = cand_pk[wv][j + u];
#pragma unroll
            for (int u = 0; u < 8; ++u) {
                r0 += (b[u] > pk0);
                r1 += (b[u] > pk1);
            }
        }
        if (i0 >= 0 && r0 < KK) EMIT(r0, i0, v0);
        if (i1 >= 0 && r1 < KK) EMIT(r1, i1, v1);
        done = true;
    }

    if (!done) {
        // ---- Fallback (cold, exact): full-row re-read bisection -----------
        unsigned lo = 0u, hi = 0x7F800000u;
        unsigned tb = 0u;
        bool exact = false;
        while (hi - lo > 1u) {
            unsigned mid = (lo + hi) >> 1;
            float tm = __uint_as_float(mid);
            int c = 0;
            for (int j = 0; j < 32; ++j) {
                float av = Ar[j * 64 + lane];
                float nv = Nr[j * 64 + lane];
                float k = fmaf(nv, 1e-4f, fmaxf(av, 0.f));
                c += __popcll(__ballot(k >= tm));
            }
            if (c == KK) { tb = mid; exact = true; break; }
            if (c > KK) lo = mid; else hi = mid;
        }
        if (exact) {
            float t = __uint_as_float(tb);
            int run = 0;
            for (int j = 0; j < 32; ++j) {
                float av = Ar[j * 64 + lane];
                float nv = Nr[j * 64 + lane];
                float v = fmaxf(av, 0.f);
                float k = fmaf(nv, 1e-4f, v);
                bool p = k >= t;
                unsigned long long m = __ballot(p);
                if (p) EMIT(run + __popcll(m & ltm), j * 64 + lane, v);
                run += __popcll(m);
            }
        } else {
            // Exact tie at the K/K+1 boundary: strictly-greater first, then
            // ascending-index among ties (lax.top_k semantics).
            float t1 = __uint_as_float(lo);
            int run = 0;
            for (int j = 0; j < 32; ++j) {
                float av = Ar[j * 64 + lane];
                float nv = Nr[j * 64 + lane];
                float v = fmaxf(av, 0.f);
                float k = fmaf(nv, 1e-4f, v);
                bool p = k > t1;
                unsigned long long m = __ballot(p);
                if (p) EMIT(run + __popcll(m & ltm), j * 64 + lane, v);
                run += __popcll(m);
            }
            if (lane == 0) tie_cnt[wv] = 0;
            for (int j = 0; j < 32; ++j) {
                float av = Ar[j * 64 + lane];
                float nv = Nr[j * 64 + lane];
                float k = fmaf(nv, 1e-4f, fmaxf(av, 0.f));
                if (k == t1) {
                    int p = atomicAdd(&tie_cnt[wv], 1);
                    if (p < 64) tie_idx[wv][p] = j * 64 + lane;
                }
            }
            if (lane == 0) {
                int n = tie_cnt[wv]; if (n > 64) n = 64;
                int need = KK - run;
                for (int s = 0; s < need; ++s) {
                    int bq = 0, bidx = 0x7fffffff;
                    for (int q = 0; q < n; ++q) {
                        int v = tie_idx[wv][q];
                        if (v < bidx) { bidx = v; bq = q; }
                    }
                    tie_idx[wv][bq] = 0x7fffffff;
                    float v = fmaxf(Ar[bidx], 0.f);
                    EMIT(run + s, bidx, v);
                }
            }
        }
    }
#undef EMIT
}

// ---------------------------------------------------------------------------
// Kernel 2: dinv = (1 + 0.5*(rowsum + colsum))^-1/2.
// ---------------------------------------------------------------------------
__global__ __launch_bounds__(256) void dinv_kernel(
    const float* __restrict__ sel_val, const float* __restrict__ colsum,
    float* __restrict__ dinv)
{
    int r = blockIdx.x * 256 + threadIdx.x;        // 0 .. 32767
    const float* svp = sel_val + (size_t)r * KK;
    float rs = 0.f;
#pragma unroll
    for (int k = 0; k < KK; ++k) rs += svp[k];
    float d = 1.0f + 0.5f * (rs + colsum[r]);
    dinv[r] = 1.0f / sqrtf(d);                     // d >= 1 always
}

// ---------------------------------------------------------------------------
// Kernel 3 (v6): global scatter onto memset-zeroed output. Output is 99%
// zeros (mean 41 nonzeros / 2048 per row); instead of staging every row
// through LDS (dense_row: full 8KB zero+atomics+read per row, block-serial),
// one thread per (row,k) issues TWO fire-and-forget global atomicAdds:
//   out[r][j] += w  and  out[j][r] += w,  w = 0.5*v*d_r*d_j
// plus one thread per row for the diagonal d_r^2. Atomicity exactly handles
// mutual selection (r in topk(j) and j in topk(r)) and self-loops.
// ---------------------------------------------------------------------------
__global__ __launch_bounds__(256) void scatter_kernel(
    const int* __restrict__ sel_idx, const float* __restrict__ sel_val,
    const float* __restrict__ dinv, float* __restrict__ out)
{
    int tid = blockIdx.x * 256 + threadIdx.x;      // 0 .. 32768*21-1
    int r = tid / 21;                              // magic-mul division
    int s = tid - r * 21;
    const int colbase = r & ~(NN - 1);
    const int i = r & (NN - 1);
    float dr = dinv[r];

    if (s == 20) {
        // (A+I) diagonal term
        atomicAdd(&out[(size_t)r * NN + i], dr * dr);
    } else {
        int   j = sel_idx[(size_t)r * KK + s];
        float v = sel_val[(size_t)r * KK + s];
        float w = 0.5f * v * dr * dinv[colbase + j];
        atomicAdd(&out[(size_t)r * NN + j], w);
        atomicAdd(&out[(size_t)(colbase + j) * NN + i], w);
    }
}

// ---------------------------------------------------------------------------
extern "C" void kernel_launch(void* const* d_in, const int* in_sizes, int n_in,
                              void* d_out, int out_size, void* d_ws, size_t ws_size,
                              hipStream_t stream)
{
    const float* A     = (const float*)d_in[0];
    const float* noise = (const float*)d_in[1];
    float* out = (float*)d_out;
    char*  ws  = (char*)d_ws;

    const int rows = BB * NN;                      // 32768
    // workspace layout (~5.5 MB total)
    size_t off = 0;
    int*   sel_idx = (int*)(ws + off);            off += (size_t)rows * KK * 4;   // 2.62 MB
    float* sel_val = (float*)(ws + off);          off += (size_t)rows * KK * 4;   // 2.62 MB
    float* colsum  = (float*)(ws + off);          off += (size_t)rows * 4;        // 128 KB
    float* dinv    = (float*)(ws + off);                                          // 128 KB

    hipMemsetAsync(out, 0, (size_t)out_size, stream);
    hipMemsetAsync(colsum, 0, rows * sizeof(float), stream);

    topk_kernel<<<rows / 4, 256, 0, stream>>>(A, noise, sel_idx, sel_val, colsum);
    dinv_kernel<<<rows / 256, 256, 0, stream>>>(sel_val, colsum, dinv);
    scatter_kernel<<<rows * 21 / 256, 256, 0, stream>>>(sel_idx, sel_val, dinv, out);
}